// Round 1
// baseline (1650.326 us; speedup 1.0000x reference)
//
#include <hip/hip_runtime.h>
#include <stdint.h>

#define TT 16384
#define HH 4096

typedef uint8_t u8;
typedef uint32_t u32;
typedef __attribute__((ext_vector_type(4))) float f32x4;

// ---- fp8 e4m3 (OCP) pack: 4 floats -> 4 bytes, RNE, saturating ----
__device__ __forceinline__ u32 cvt4_fp8(float a, float b, float c, float d) {
  u32 v = 0;
  v = __builtin_amdgcn_cvt_pk_fp8_f32(a, b, v, false);  // low word
  v = __builtin_amdgcn_cvt_pk_fp8_f32(c, d, v, true);   // high word
  return v;
}

__device__ __forceinline__ void gl_lds16(const void* g, void* l) {
  __builtin_amdgcn_global_load_lds(
      (const __attribute__((address_space(1))) void*)g,
      (__attribute__((address_space(3))) void*)l, 16, 0, 0);
}

// ---- weight quantize + transpose: w[K][N] fp32 (already on fp8 grid) -> wq[N][K] fp8
__global__ __launch_bounds__(256) void kwquant(const float* __restrict__ w,
                                               u8* __restrict__ wq) {
  __shared__ __align__(16) u8 tile[64][68];
  const int n0 = blockIdx.x * 64;
  const int k0 = blockIdx.y * 64;
  const int t = threadIdx.x;
  const int tr = t >> 4, tc = t & 15;
#pragma unroll
  for (int p = 0; p < 4; ++p) {
    const int kl = p * 16 + tr;
    const float4 v = *(const float4*)(w + (size_t)(k0 + kl) * HH + n0 + tc * 4);
    const u32 pk = cvt4_fp8(v.x, v.y, v.z, v.w);
    tile[tc * 4 + 0][kl] = (u8)(pk);
    tile[tc * 4 + 1][kl] = (u8)(pk >> 8);
    tile[tc * 4 + 2][kl] = (u8)(pk >> 16);
    tile[tc * 4 + 3][kl] = (u8)(pk >> 24);
  }
  __syncthreads();
  const int jr = t >> 2;
  const int kc = (t & 3) * 16;
  u32 o0 = *(const u32*)&tile[jr][kc + 0];
  u32 o1 = *(const u32*)&tile[jr][kc + 4];
  u32 o2 = *(const u32*)&tile[jr][kc + 8];
  u32 o3 = *(const u32*)&tile[jr][kc + 12];
  uint4 ov; ov.x = o0; ov.y = o1; ov.z = o2; ov.w = o3;
  *(uint4*)(wq + (size_t)(n0 + jr) * HH + k0 + kc) = ov;
}

__device__ __forceinline__ float wred_sum(float v) {
#pragma unroll
  for (int o = 32; o; o >>= 1) v += __shfl_down(v, o, 64);
  return v;
}
__device__ __forceinline__ float wred_max(float v) {
#pragma unroll
  for (int o = 32; o; o >>= 1) v = fmaxf(v, __shfl_down(v, o, 64));
  return v;
}

// MODE 0: src=x, write resid=sqrt(x) to resid_out, quantize rmsnorm(x,nw) -> qout,sout
// MODE 1: src=resid, quantize rmsnorm(resid,nw) -> qout,sout
// MODE 2: src=resid, write y=rmsnorm(resid,nw) fp32 -> yout (may alias src)
template <int MODE>
__global__ __launch_bounds__(256) void knorm(const float* __restrict__ src,
                                             const float* __restrict__ nw,
                                             float* __restrict__ resid_out,
                                             u8* __restrict__ qout,
                                             float* __restrict__ sout,
                                             float* __restrict__ yout) {
  __shared__ float red[4];
  __shared__ float redm[4];
  const int row = blockIdx.x;
  const int t = threadIdx.x;
  const int lane = t & 63, wid = t >> 6;
  const float* rp = src + (size_t)row * HH;

  float4 xv[4];
  float ssq = 0.f;
#pragma unroll
  for (int p = 0; p < 4; ++p) {
    xv[p] = *((const float4*)rp + p * 256 + t);
    ssq += xv[p].x * xv[p].x;
    ssq += xv[p].y * xv[p].y;
    ssq += xv[p].z * xv[p].z;
    ssq += xv[p].w * xv[p].w;
  }
  if (MODE == 0) {
    float* rr = resid_out + (size_t)row * HH;
#pragma unroll
    for (int p = 0; p < 4; ++p) {
      float4 r4;
      r4.x = sqrtf(xv[p].x); r4.y = sqrtf(xv[p].y);
      r4.z = sqrtf(xv[p].z); r4.w = sqrtf(xv[p].w);
      *((float4*)rr + p * 256 + t) = r4;
    }
  }
  ssq = wred_sum(ssq);
  if (lane == 0) red[wid] = ssq;
  __syncthreads();
  const float ms = (((red[0] + red[1]) + red[2]) + red[3]) * (1.0f / HH);
  const float inv = 1.0f / sqrtf(ms + 1e-6f);

  float y[16];
  float amax = 0.f;
#pragma unroll
  for (int p = 0; p < 4; ++p) {
    const float4 wv = *((const float4*)nw + p * 256 + t);
    y[p * 4 + 0] = (xv[p].x * inv) * wv.x;
    y[p * 4 + 1] = (xv[p].y * inv) * wv.y;
    y[p * 4 + 2] = (xv[p].z * inv) * wv.z;
    y[p * 4 + 3] = (xv[p].w * inv) * wv.w;
    amax = fmaxf(amax, fabsf(y[p * 4 + 0]));
    amax = fmaxf(amax, fabsf(y[p * 4 + 1]));
    amax = fmaxf(amax, fabsf(y[p * 4 + 2]));
    amax = fmaxf(amax, fabsf(y[p * 4 + 3]));
  }

  if (MODE == 2) {
    float* yp = yout + (size_t)row * HH;
#pragma unroll
    for (int p = 0; p < 4; ++p) {
      float4 o;
      o.x = y[p * 4 + 0]; o.y = y[p * 4 + 1];
      o.z = y[p * 4 + 2]; o.w = y[p * 4 + 3];
      *((float4*)yp + p * 256 + t) = o;
    }
    return;
  }

  amax = wred_max(amax);
  if (lane == 0) redm[wid] = amax;
  __syncthreads();
  const float bmax = fmaxf(fmaxf(redm[0], redm[1]), fmaxf(redm[2], redm[3]));
  const float sval = fmaxf(bmax / 448.0f, 1e-10f);  // matches ref: max|y|/448, floor 1e-10

  u32* qp = (u32*)(qout + (size_t)row * HH);
#pragma unroll
  for (int p = 0; p < 4; ++p) {
    float q0 = fminf(fmaxf(y[p * 4 + 0] / sval, -448.f), 448.f);
    float q1 = fminf(fmaxf(y[p * 4 + 1] / sval, -448.f), 448.f);
    float q2 = fminf(fmaxf(y[p * 4 + 2] / sval, -448.f), 448.f);
    float q3 = fminf(fmaxf(y[p * 4 + 3] / sval, -448.f), 448.f);
    qp[p * 256 + t] = cvt4_fp8(q0, q1, q2, q3);
  }
  if (t == 0) sout[row] = sval;
}

// ---- fp8 GEMM: C[t,j] = sum_k Aq[t,k]*Bq[j,k]; resid[t,j] += C*s[t]*wsc[j]
// 128x128 tile, BK=64, 4 waves (2x2), each wave 64x64 via 4x4 16x16x32 mfma frags.
// LDS layout: row-major [128][64] bytes with byte-XOR swizzle c ^= (r&3)<<4
// (kept consistent between pre-swizzled global_load_lds source and ds_read).
__global__ __launch_bounds__(256) void kgemm(const u8* __restrict__ Aq,
                                             const u8* __restrict__ Bq,
                                             const float* __restrict__ srow,
                                             const float* __restrict__ wsc,
                                             float* __restrict__ resid) {
  constexpr int K = HH, N = HH;
  __shared__ __align__(16) u8 smA[128 * 64];
  __shared__ __align__(16) u8 smB[128 * 64];

  const int nwg = 4096;
  int bid = blockIdx.x;
  bid = (bid & 7) * (nwg >> 3) + (bid >> 3);  // XCD-bijective swizzle (4096%8==0)
  const int tm = bid >> 5;   // 128 M-tiles
  const int tn = bid & 31;   // 32 N-tiles
  const int row0 = tm * 128, col0 = tn * 128;

  const int t = threadIdx.x;
  const int lane = t & 63, wid = t >> 6;
  const int wr = wid >> 1, wc = wid & 1;

  f32x4 acc[4][4];
#pragma unroll
  for (int m = 0; m < 4; ++m)
#pragma unroll
    for (int n = 0; n < 4; ++n) acc[m][n] = (f32x4)0.f;

  int aoffg[2], boffg[2], ldso[2];
#pragma unroll
  for (int p = 0; p < 2; ++p) {
    const int off = (wid * 2 + p) * 1024 + lane * 16;
    const int r = off >> 6;
    const int c = (off & 63) ^ ((r & 3) << 4);  // inverse-swizzled global source
    aoffg[p] = (row0 + r) * K + c;
    boffg[p] = (col0 + r) * K + c;
    ldso[p] = (wid * 2 + p) * 1024;
  }

  for (int k0 = 0; k0 < K; k0 += 64) {
#pragma unroll
    for (int p = 0; p < 2; ++p) {
      gl_lds16(Aq + aoffg[p] + k0, smA + ldso[p]);
      gl_lds16(Bq + boffg[p] + k0, smB + ldso[p]);
    }
    asm volatile("s_waitcnt vmcnt(0)" ::: "memory");
    __syncthreads();

#pragma unroll
    for (int kk = 0; kk < 2; ++kk) {
      long long av[4], bv[4];
#pragma unroll
      for (int m = 0; m < 4; ++m) {
        const int r = wr * 64 + m * 16 + (lane & 15);
        const int c = kk * 32 + (lane >> 4) * 8;
        av[m] = *(const long long*)(smA + r * 64 + (c ^ ((r & 3) << 4)));
      }
#pragma unroll
      for (int n = 0; n < 4; ++n) {
        const int r = wc * 64 + n * 16 + (lane & 15);
        const int c = kk * 32 + (lane >> 4) * 8;
        bv[n] = *(const long long*)(smB + r * 64 + (c ^ ((r & 3) << 4)));
      }
#pragma unroll
      for (int m = 0; m < 4; ++m)
#pragma unroll
        for (int n = 0; n < 4; ++n)
          acc[m][n] = __builtin_amdgcn_mfma_f32_16x16x32_fp8_fp8(av[m], bv[n],
                                                                 acc[m][n], 0, 0, 0);
    }
    __syncthreads();
  }

  // epilogue: resid += (acc * s_token) * wscale_col   (C/D: col=lane&15, row=(lane>>4)*4+i)
  const int lr = lane >> 4, lc = lane & 15;
  float wv[4];
#pragma unroll
  for (int n = 0; n < 4; ++n) wv[n] = wsc[col0 + wc * 64 + n * 16 + lc];
#pragma unroll
  for (int m = 0; m < 4; ++m) {
#pragma unroll
    for (int i = 0; i < 4; ++i) {
      const int row = row0 + wr * 64 + m * 16 + lr * 4 + i;
      const float sv = srow[row];
#pragma unroll
      for (int n = 0; n < 4; ++n) {
        const int col = col0 + wc * 64 + n * 16 + lc;
        const size_t idx = (size_t)row * N + col;
        resid[idx] = resid[idx] + (acc[m][n][i] * sv) * wv[n];
      }
    }
  }
}

extern "C" void kernel_launch(void* const* d_in, const int* in_sizes, int n_in,
                              void* d_out, int out_size, void* d_ws, size_t ws_size,
                              hipStream_t stream) {
  const float* x   = (const float*)d_in[0];
  const float* nw0 = (const float*)d_in[1];
  const float* nw1 = (const float*)d_in[2];
  const float* nw2 = (const float*)d_in[3];
  const float* w0  = (const float*)d_in[4];
  const float* w1  = (const float*)d_in[5];
  const float* ws0 = (const float*)d_in[6];
  const float* ws1 = (const float*)d_in[7];
  float* out = (float*)d_out;

  // workspace: q (T*H fp8) | w0q (H*H fp8) | w1q (H*H fp8) | s (T fp32)  ~= 96.1 MiB
  u8* q = (u8*)d_ws;
  u8* w0q = q + (size_t)TT * HH;
  u8* w1q = w0q + (size_t)HH * HH;
  float* sbuf = (float*)(w1q + (size_t)HH * HH);

  dim3 wg(HH / 64, HH / 64);
  kwquant<<<wg, 256, 0, stream>>>(w0, w0q);
  kwquant<<<wg, 256, 0, stream>>>(w1, w1q);

  knorm<0><<<TT, 256, 0, stream>>>(x, nw0, out, q, sbuf, nullptr);
  kgemm<<<(TT / 128) * (HH / 128), 256, 0, stream>>>(q, w0q, sbuf, ws0, out);
  knorm<1><<<TT, 256, 0, stream>>>(out, nw1, nullptr, q, sbuf, nullptr);
  kgemm<<<(TT / 128) * (HH / 128), 256, 0, stream>>>(q, w1q, sbuf, ws1, out);
  knorm<2><<<TT, 256, 0, stream>>>(out, nw2, nullptr, nullptr, nullptr, out);
}

// Round 2
// 1332.910 us; speedup vs baseline: 1.2381x; 1.2381x over previous
//
#include <hip/hip_runtime.h>
#include <stdint.h>

#define TT 16384
#define HH 4096

typedef uint8_t u8;
typedef uint32_t u32;
typedef __attribute__((ext_vector_type(4))) float f32x4;

// ---- fp8 e4m3 (OCP) pack: 4 floats -> 4 bytes, RNE, saturating ----
__device__ __forceinline__ u32 cvt4_fp8(float a, float b, float c, float d) {
  u32 v = 0;
  v = __builtin_amdgcn_cvt_pk_fp8_f32(a, b, v, false);  // low word
  v = __builtin_amdgcn_cvt_pk_fp8_f32(c, d, v, true);   // high word
  return v;
}

__device__ __forceinline__ void gl_lds16(const void* g, void* l) {
  __builtin_amdgcn_global_load_lds(
      (const __attribute__((address_space(1))) void*)g,
      (__attribute__((address_space(3))) void*)l, 16, 0, 0);
}

// ---- weight quantize + transpose: w[K][N] fp32 (already on fp8 grid) -> wq[N][K] fp8
__global__ __launch_bounds__(256) void kwquant(const float* __restrict__ w,
                                               u8* __restrict__ wq) {
  __shared__ __align__(16) u8 tile[64][68];
  const int n0 = blockIdx.x * 64;
  const int k0 = blockIdx.y * 64;
  const int t = threadIdx.x;
  const int tr = t >> 4, tc = t & 15;
#pragma unroll
  for (int p = 0; p < 4; ++p) {
    const int kl = p * 16 + tr;
    const float4 v = *(const float4*)(w + (size_t)(k0 + kl) * HH + n0 + tc * 4);
    const u32 pk = cvt4_fp8(v.x, v.y, v.z, v.w);
    tile[tc * 4 + 0][kl] = (u8)(pk);
    tile[tc * 4 + 1][kl] = (u8)(pk >> 8);
    tile[tc * 4 + 2][kl] = (u8)(pk >> 16);
    tile[tc * 4 + 3][kl] = (u8)(pk >> 24);
  }
  __syncthreads();
  const int jr = t >> 2;
  const int kc = (t & 3) * 16;
  u32 o0 = *(const u32*)&tile[jr][kc + 0];
  u32 o1 = *(const u32*)&tile[jr][kc + 4];
  u32 o2 = *(const u32*)&tile[jr][kc + 8];
  u32 o3 = *(const u32*)&tile[jr][kc + 12];
  uint4 ov; ov.x = o0; ov.y = o1; ov.z = o2; ov.w = o3;
  *(uint4*)(wq + (size_t)(n0 + jr) * HH + k0 + kc) = ov;
}

__device__ __forceinline__ float wred_sum(float v) {
#pragma unroll
  for (int o = 32; o; o >>= 1) v += __shfl_down(v, o, 64);
  return v;
}
__device__ __forceinline__ float wred_max(float v) {
#pragma unroll
  for (int o = 32; o; o >>= 1) v = fmaxf(v, __shfl_down(v, o, 64));
  return v;
}

// MODE 0: src=x, write resid=sqrt(x) to resid_out, quantize rmsnorm(x,nw) -> qout,sout
// MODE 1: src=resid, quantize rmsnorm(resid,nw) -> qout,sout
// MODE 2: src=resid, write y=rmsnorm(resid,nw) fp32 -> yout (may alias src)
template <int MODE>
__global__ __launch_bounds__(256) void knorm(const float* __restrict__ src,
                                             const float* __restrict__ nw,
                                             float* __restrict__ resid_out,
                                             u8* __restrict__ qout,
                                             float* __restrict__ sout,
                                             float* __restrict__ yout) {
  __shared__ float red[4];
  __shared__ float redm[4];
  const int row = blockIdx.x;
  const int t = threadIdx.x;
  const int lane = t & 63, wid = t >> 6;
  const float* rp = src + (size_t)row * HH;

  float4 xv[4];
  float ssq = 0.f;
#pragma unroll
  for (int p = 0; p < 4; ++p) {
    xv[p] = *((const float4*)rp + p * 256 + t);
    ssq += xv[p].x * xv[p].x;
    ssq += xv[p].y * xv[p].y;
    ssq += xv[p].z * xv[p].z;
    ssq += xv[p].w * xv[p].w;
  }
  if (MODE == 0) {
    float* rr = resid_out + (size_t)row * HH;
#pragma unroll
    for (int p = 0; p < 4; ++p) {
      float4 r4;
      r4.x = sqrtf(xv[p].x); r4.y = sqrtf(xv[p].y);
      r4.z = sqrtf(xv[p].z); r4.w = sqrtf(xv[p].w);
      *((float4*)rr + p * 256 + t) = r4;
    }
  }
  ssq = wred_sum(ssq);
  if (lane == 0) red[wid] = ssq;
  __syncthreads();
  const float ms = (((red[0] + red[1]) + red[2]) + red[3]) * (1.0f / HH);
  const float inv = 1.0f / sqrtf(ms + 1e-6f);

  float y[16];
  float amax = 0.f;
#pragma unroll
  for (int p = 0; p < 4; ++p) {
    const float4 wv = *((const float4*)nw + p * 256 + t);
    y[p * 4 + 0] = (xv[p].x * inv) * wv.x;
    y[p * 4 + 1] = (xv[p].y * inv) * wv.y;
    y[p * 4 + 2] = (xv[p].z * inv) * wv.z;
    y[p * 4 + 3] = (xv[p].w * inv) * wv.w;
    amax = fmaxf(amax, fabsf(y[p * 4 + 0]));
    amax = fmaxf(amax, fabsf(y[p * 4 + 1]));
    amax = fmaxf(amax, fabsf(y[p * 4 + 2]));
    amax = fmaxf(amax, fabsf(y[p * 4 + 3]));
  }

  if (MODE == 2) {
    float* yp = yout + (size_t)row * HH;
#pragma unroll
    for (int p = 0; p < 4; ++p) {
      float4 o;
      o.x = y[p * 4 + 0]; o.y = y[p * 4 + 1];
      o.z = y[p * 4 + 2]; o.w = y[p * 4 + 3];
      *((float4*)yp + p * 256 + t) = o;
    }
    return;
  }

  amax = wred_max(amax);
  if (lane == 0) redm[wid] = amax;
  __syncthreads();
  const float bmax = fmaxf(fmaxf(redm[0], redm[1]), fmaxf(redm[2], redm[3]));
  const float sval = fmaxf(bmax / 448.0f, 1e-10f);  // matches ref: max|y|/448, floor 1e-10

  u32* qp = (u32*)(qout + (size_t)row * HH);
#pragma unroll
  for (int p = 0; p < 4; ++p) {
    float q0 = fminf(fmaxf(y[p * 4 + 0] / sval, -448.f), 448.f);
    float q1 = fminf(fmaxf(y[p * 4 + 1] / sval, -448.f), 448.f);
    float q2 = fminf(fmaxf(y[p * 4 + 2] / sval, -448.f), 448.f);
    float q3 = fminf(fmaxf(y[p * 4 + 3] / sval, -448.f), 448.f);
    qp[p * 256 + t] = cvt4_fp8(q0, q1, q2, q3);
  }
  if (t == 0) sout[row] = sval;
}

// ---- fp8 GEMM: C[t,j] = sum_k Aq[t,k]*Bq[j,k]; resid[t,j] += C*s[t]*wsc[j]
// 128x128 tile, BK=64, 4 waves (2x2), each wave 64x64 via 4x4 16x16x32 mfma frags.
// LDS: double-buffered row-major [128][64] bytes, byte-XOR swizzle
//   c ^= ((r>>1)&3)<<4   (16B-granular; row bit0 -> bank bit4 naturally,
//   row bits 1,2 -> bank bits 2,3 injected => 8 rows spread over 8 start-banks,
//   16-row fragment read = 2-way aliasing = free per m136)
// Pipeline: 2-phase with counted vmcnt(4) (T3 minimum recipe) — raw s_barrier,
// no __syncthreads (which would force vmcnt(0) drain).
__global__ __launch_bounds__(256) void kgemm(const u8* __restrict__ Aq,
                                             const u8* __restrict__ Bq,
                                             const float* __restrict__ srow,
                                             const float* __restrict__ wsc,
                                             float* __restrict__ resid) {
  constexpr int K = HH, N = HH;
  constexpr int NT = K / 64;
  __shared__ __align__(16) u8 smA[2][128 * 64];
  __shared__ __align__(16) u8 smB[2][128 * 64];

  const int nwg = 4096;
  int bid = blockIdx.x;
  bid = (bid & 7) * (nwg >> 3) + (bid >> 3);  // XCD-bijective swizzle (4096%8==0)
  const int tm = bid >> 5;   // 128 M-tiles
  const int tn = bid & 31;   // 32 N-tiles
  const int row0 = tm * 128, col0 = tn * 128;

  const int t = threadIdx.x;
  const int lane = t & 63, wid = t >> 6;
  const int wr = wid >> 1, wc = wid & 1;

  f32x4 acc[4][4];
#pragma unroll
  for (int m = 0; m < 4; ++m)
#pragma unroll
    for (int n = 0; n < 4; ++n) acc[m][n] = (f32x4)0.f;

  int aoffg[2], boffg[2], ldso[2];
#pragma unroll
  for (int p = 0; p < 2; ++p) {
    const int off = (wid * 2 + p) * 1024 + lane * 16;
    const int r = off >> 6;
    const int c = (off & 63) ^ (((r >> 1) & 3) << 4);  // inverse-swizzled global source
    aoffg[p] = (row0 + r) * K + c;
    boffg[p] = (col0 + r) * K + c;
    ldso[p] = off;
  }

  // prologue: stage tile 0 into buf 0
#pragma unroll
  for (int p = 0; p < 2; ++p) {
    gl_lds16(Aq + aoffg[p], smA[0] + ldso[p]);
    gl_lds16(Bq + boffg[p], smB[0] + ldso[p]);
  }

  for (int it = 0; it < NT; ++it) {
    const int k0 = it * 64;
    if (it + 1 < NT) {
      const int nb = (it + 1) & 1;
#pragma unroll
      for (int p = 0; p < 2; ++p) {
        gl_lds16(Aq + aoffg[p] + k0 + 64, smA[nb] + ldso[p]);
        gl_lds16(Bq + boffg[p] + k0 + 64, smB[nb] + ldso[p]);
      }
      asm volatile("s_waitcnt vmcnt(4)" ::: "memory");  // current tile landed; next 4 in flight
    } else {
      asm volatile("s_waitcnt vmcnt(0)" ::: "memory");
    }
    __builtin_amdgcn_s_barrier();
    __builtin_amdgcn_sched_barrier(0);

    const u8* sA = smA[it & 1];
    const u8* sB = smB[it & 1];
#pragma unroll
    for (int kk = 0; kk < 2; ++kk) {
      long long av[4], bv[4];
#pragma unroll
      for (int m = 0; m < 4; ++m) {
        const int r = wr * 64 + m * 16 + (lane & 15);
        const int c = (kk * 32 + (lane >> 4) * 8) ^ (((r >> 1) & 3) << 4);
        av[m] = *(const long long*)(sA + r * 64 + c);
      }
#pragma unroll
      for (int n = 0; n < 4; ++n) {
        const int r = wc * 64 + n * 16 + (lane & 15);
        const int c = (kk * 32 + (lane >> 4) * 8) ^ (((r >> 1) & 3) << 4);
        bv[n] = *(const long long*)(sB + r * 64 + c);
      }
#pragma unroll
      for (int m = 0; m < 4; ++m)
#pragma unroll
        for (int n = 0; n < 4; ++n)
          acc[m][n] = __builtin_amdgcn_mfma_f32_16x16x32_fp8_fp8(av[m], bv[n],
                                                                 acc[m][n], 0, 0, 0);
    }
    __builtin_amdgcn_sched_barrier(0);
    __builtin_amdgcn_s_barrier();
  }

  // epilogue: resid += (acc * s_token) * wscale_col   (C/D: col=lane&15, row=(lane>>4)*4+i)
  const int lr = lane >> 4, lc = lane & 15;
  float wv[4];
#pragma unroll
  for (int n = 0; n < 4; ++n) wv[n] = wsc[col0 + wc * 64 + n * 16 + lc];
#pragma unroll
  for (int m = 0; m < 4; ++m) {
#pragma unroll
    for (int i = 0; i < 4; ++i) {
      const int row = row0 + wr * 64 + m * 16 + lr * 4 + i;
      const float sv = srow[row];
#pragma unroll
      for (int n = 0; n < 4; ++n) {
        const int col = col0 + wc * 64 + n * 16 + lc;
        const size_t idx = (size_t)row * N + col;
        resid[idx] = resid[idx] + (acc[m][n][i] * sv) * wv[n];
      }
    }
  }
}

extern "C" void kernel_launch(void* const* d_in, const int* in_sizes, int n_in,
                              void* d_out, int out_size, void* d_ws, size_t ws_size,
                              hipStream_t stream) {
  const float* x   = (const float*)d_in[0];
  const float* nw0 = (const float*)d_in[1];
  const float* nw1 = (const float*)d_in[2];
  const float* nw2 = (const float*)d_in[3];
  const float* w0  = (const float*)d_in[4];
  const float* w1  = (const float*)d_in[5];
  const float* ws0 = (const float*)d_in[6];
  const float* ws1 = (const float*)d_in[7];
  float* out = (float*)d_out;

  // workspace: q (T*H fp8) | w0q (H*H fp8) | w1q (H*H fp8) | s (T fp32)  ~= 96.1 MiB
  u8* q = (u8*)d_ws;
  u8* w0q = q + (size_t)TT * HH;
  u8* w1q = w0q + (size_t)HH * HH;
  float* sbuf = (float*)(w1q + (size_t)HH * HH);

  dim3 wg(HH / 64, HH / 64);
  kwquant<<<wg, 256, 0, stream>>>(w0, w0q);
  kwquant<<<wg, 256, 0, stream>>>(w1, w1q);

  knorm<0><<<TT, 256, 0, stream>>>(x, nw0, out, q, sbuf, nullptr);
  kgemm<<<(TT / 128) * (HH / 128), 256, 0, stream>>>(q, w0q, sbuf, ws0, out);
  knorm<1><<<TT, 256, 0, stream>>>(out, nw1, nullptr, q, sbuf, nullptr);
  kgemm<<<(TT / 128) * (HH / 128), 256, 0, stream>>>(q, w1q, sbuf, ws1, out);
  knorm<2><<<TT, 256, 0, stream>>>(out, nw2, nullptr, nullptr, nullptr, out);
}